// Round 11
// baseline (140.744 us; speedup 1.0000x reference)
//
#include <hip/hip_runtime.h>

// CRF loss, B=1024, T=512, K=32 — chunked associative scan, FULLY FUSED,
// A-SIDE SCALING: zero in-loop LDS (r11 experiment).
//
// One WG (256 thr = 4 waves) per sequence; wave wv owns chunks 2wv, 2wv+1
// (NCH=8, CHL=64), steps interleaved. r4-r10 ledger: ~62-72 µs invariant
// across {4,8,16} chains/SIMD, VALU cuts, occupancy 30-58% -> concurrency,
// VALU count and occupancy exonerated. Last structural suspect: the per-step
// ds_read_b128 broadcasts feeding the scale muls ON the serial chain
// (MFMA->scale->pack->MFMA) with CU-shared LDS under 16-32-wave load.
//
// This version uses D_t (A N) = (D_t A) N with the A-fragment's row-per-lane
// layout (AE0 = row n, AE1 = row 16+n — how the constants were always
// packed): per step each lane needs only d[n], d[16+n], gathered by 2
// ds_bpermute from emit exps held in REGISTERS (8 coalesced dword loads +
// 8 exps per 16-step stage, packed t-major: ev[j] lane l =
// exp(emit[t0+2j+(l>>5)][l&31])). At = pack_bf16(d x AF_f32) is built OFF
// the critical chain (independent of N); 4 MFMAs emit final C (no post
// scale); chain is MFMA->pack(C->B)->MFMA. NO ds_read/ds_write in the loop.
//
//   * step = 2 bpermute + 16 mul + 8 pack(At) + 4 mfma + 8 pack(C->B)
//   * renorm every 8 steps: exact pow2 exponent strip (SALU, off-chain-ish)
//   * launch_bounds(256,4): VGPR cap 128 (r6 lesson: 2nd arg = WG/CU;
//     WRITE_SIZE is the spill canary, must stay ~32 B)
//   * epilogue + combine: r8 VERBATIM (proven): two transposes through
//     stride-20 scratch at +1024, M^T dumps at 0/512, wave-0 8-matvec
//     combine with rolling register prefetch.
//
// Per-wave LDS (2048 dwords = expAll[wv], used ONLY by the epilogue):
//   scratch [1024..1663]; M^T A -> [0..511], M^T B -> [512..1023]
//   sAux: [0..3] per-wave Slog, [4..7] per-wave path-score

#define K32 32
#define Tt  512
#define NCH 8
#define CHL 64
#define NSTG 4
#define STL 16

typedef float  float4v __attribute__((ext_vector_type(4)));
typedef short  short8v __attribute__((ext_vector_type(8)));

__device__ inline float bf2f_lo(unsigned d) { return __uint_as_float(d << 16); }
__device__ inline float bf2f_hi(unsigned d) { return __uint_as_float(d & 0xFFFF0000u); }

// pack two f32 -> bf16x2 dword by truncation: low16 = hi16(lo), high16 = hi16(hi)
__device__ inline unsigned pack_trunc(float hi, float lo) {
    return __builtin_amdgcn_perm(__float_as_uint(hi), __float_as_uint(lo), 0x07060302u);
}
__device__ inline float bperm(int addr, float v) {
    return __int_as_float(__builtin_amdgcn_ds_bpermute(addr, __float_as_int(v)));
}

union F8 { unsigned u[4]; short8v v; };

__global__ __launch_bounds__(256, 4) void crf_fused(
    const int*   __restrict__ labels,
    const float* __restrict__ y_pred,
    const float* __restrict__ trans,
    const float* __restrict__ mask,
    float*       __restrict__ out)
{
    __shared__ float expAll[4][2048];         // 32 KB -> 4 WG/CU (epilogue only)
    __shared__ float sAux[8];

    const int lane = threadIdx.x & 63;
    const int wv   = __builtin_amdgcn_readfirstlane(threadIdx.x >> 6);  // wave-uniform
    const int n    = lane & 15;
    const int q    = lane >> 4;
    const int seq  = blockIdx.x;              // scalar

    float* ebA = &expAll[wv][0];

    const float* yp  = y_pred + (size_t)seq * Tt * K32;
    const int*   lb  = labels + (size_t)seq * Tt;
    const float* mkp = mask   + (size_t)seq * Tt;
    const int tbA = wv * 128;                 // chunk 2wv
    const int tbB = tbA + 64;                 // chunk 2wv+1

    // ---- path scores + mask ballots for both chunks (r8-proven) ----
    float sc;
    float mA, mB;
    {
        const int tA = tbA + lane;            // max 447 -> trans term always valid
        const int labA = lb[tA];
        mA = mkp[tA];
        float s = yp[tA * K32 + labA] * mA;
        s += trans[labA * K32 + lb[tA + 1]] * (mA * mkp[tA + 1]);

        const int tB = tbB + lane;            // max 511 -> guard last
        const int labB = lb[tB];
        mB = mkp[tB];
        float sB = yp[tB * K32 + labB] * mB;
        if (tB < Tt - 1) sB += trans[labB * K32 + lb[tB + 1]] * (mB * mkp[tB + 1]);

        sc = s + sB;
#pragma unroll
        for (int sft = 1; sft < 64; sft <<= 1) sc += __shfl_xor(sc, sft, 64);
    }
    unsigned long long mbA = __ballot(mA != 0.0f);
    unsigned long long mbB = __ballot(mB != 0.0f);
    if (wv == 0) mbA &= ~1ull;                // skip t=0 (alpha0 seeds combine)
    const int applied = __popcll(mbA) + __popcll(mbB);

    // ---- constant A rows in f32, pi-k-order (row n -> AF0, row 16+n -> AF1) ----
    float AF0[8], AF1[8];
#pragma unroll
    for (int h = 0; h < 4; ++h) {
        const int k0 = (h < 2) ? (q * 4 + 2 * h) : (16 + q * 4 + 2 * (h - 2));
        const int k1 = k0 + 1;
        AF0[2 * h]     = __expf(trans[k0 * K32 + n]) * 0.03125f;
        AF0[2 * h + 1] = __expf(trans[k1 * K32 + n]) * 0.03125f;
        AF1[2 * h]     = __expf(trans[k0 * K32 + 16 + n]) * 0.03125f;
        AF1[2 * h + 1] = __expf(trans[k1 * K32 + 16 + n]) * 0.03125f;
    }

    // ---- identity B fragments (pi-order) for both chunks ----
    F8 BA0, BA1, BB0, BB1;
#pragma unroll
    for (int h = 0; h < 4; ++h) {
        const int r0 = (h < 2) ? (q * 4 + 2 * h) : (16 + q * 4 + 2 * (h - 2));
        const int r1 = r0 + 1;
        unsigned w0 = 0, w1 = 0;
        if (r0 == n)      w0 |= 0x3F80u;
        if (r1 == n)      w0 |= 0x3F800000u;
        if (r0 == 16 + n) w1 |= 0x3F80u;
        if (r1 == 16 + n) w1 |= 0x3F800000u;
        BA0.u[h] = w0; BA1.u[h] = w1;
        BB0.u[h] = w0; BB1.u[h] = w1;
    }

    // ---- bpermute byte-addresses (lane-const): parity p, halves d0/d1 ----
    const int a00 = 4 * n;                    // p=0, d[n]     (src lane n)
    const int a01 = 4 * n + 64;               // p=0, d[16+n]  (src lane 16+n)
    const int a10 = 4 * n + 128;              // p=1, d[n]     (src lane 32+n)
    const int a11 = 4 * n + 192;              // p=1, d[16+n]  (src lane 48+n)

    const float4v zf = {0.f, 0.f, 0.f, 0.f};  // hoisted MFMA C-in
    int eSum = 0;                             // pow2-renorm exponent sum

    auto stepone = [&](float ev, int par, F8& B0, F8& B1, bool ren) {
        const float d0 = bperm(par ? a10 : a00, ev);   // row scale d[n]
        const float d1 = bperm(par ? a11 : a01, ev);   // row scale d[16+n]

        F8 At0, At1;                          // (D_t A) rows n / 16+n, bf16
#pragma unroll
        for (int h = 0; h < 4; ++h) {
            At0.u[h] = pack_trunc(d0 * AF0[2 * h + 1], d0 * AF0[2 * h]);
            At1.u[h] = pack_trunc(d1 * AF1[2 * h + 1], d1 * AF1[2 * h]);
        }

        float4v c00 = __builtin_amdgcn_mfma_f32_16x16x32_bf16(At0.v, B0.v, zf, 0, 0, 0);
        float4v c01 = __builtin_amdgcn_mfma_f32_16x16x32_bf16(At0.v, B1.v, zf, 0, 0, 0);
        float4v c10 = __builtin_amdgcn_mfma_f32_16x16x32_bf16(At1.v, B0.v, zf, 0, 0, 0);
        float4v c11 = __builtin_amdgcn_mfma_f32_16x16x32_bf16(At1.v, B1.v, zf, 0, 0, 0);

        if (ren) {                            // exact pow2 renorm via exponent strip
            const unsigned cb = __builtin_amdgcn_readfirstlane(__float_as_uint(c00[0]));
            const int e = (int)((cb >> 23) & 255u) - 127;
            const float rs = __uint_as_float((unsigned)(127 - e) << 23);  // 2^-e
            c00 *= rs; c01 *= rs; c10 *= rs; c11 *= rs;
            eSum += e;
        }

        // pack C -> next B (pi-order makes this the lane's own data)
        B0.u[0] = pack_trunc(c00[1], c00[0]);
        B0.u[1] = pack_trunc(c00[3], c00[2]);
        B0.u[2] = pack_trunc(c10[1], c10[0]);
        B0.u[3] = pack_trunc(c10[3], c10[2]);
        B1.u[0] = pack_trunc(c01[1], c01[0]);
        B1.u[1] = pack_trunc(c01[3], c01[2]);
        B1.u[2] = pack_trunc(c11[1], c11[0]);
        B1.u[3] = pack_trunc(c11[3], c11[2]);
    };

    // emit sources, t-major packed: ev[j] lane l = emit[t0 + 2j + (l>>5)][l&31]
    const float* gA = yp + (size_t)tbA * K32 + lane;
    const float* gB = yp + (size_t)tbB * K32 + lane;

    for (int st = 0; st < NSTG; ++st) {
        float evA[8], evB[8];
#pragma unroll
        for (int j = 0; j < 8; ++j) evA[j] = gA[st * 512 + j * 64];
#pragma unroll
        for (int j = 0; j < 8; ++j) evB[j] = gB[st * 512 + j * 64];
#pragma unroll
        for (int j = 0; j < 8; ++j) { evA[j] = __expf(evA[j]); evB[j] = __expf(evB[j]); }

        const unsigned mA16 = (unsigned)(mbA >> (st * 16)) & 0xFFFFu;
        const unsigned mB16 = (unsigned)(mbB >> (st * 16)) & 0xFFFFu;

        if (((mA16 | 1u) == 0xFFFFu) && mB16 == 0xFFFFu) {
            // fast path (covers all-ones and wv0/st0's bit-0-cleared case)
            const bool do0 = (mA16 & 1u) != 0u;
#pragma unroll
            for (int i = 0; i < STL; ++i) {
                const bool ren = (i & 7) == 7;
                if (i > 0 || do0) stepone(evA[i >> 1], i & 1, BA0, BA1, ren);
                stepone(evB[i >> 1], i & 1, BB0, BB1, ren);
            }
        } else {
            // rare masked path — MUST stay unrolled (static reg indexing)
#pragma unroll
            for (int i = 0; i < STL; ++i) {
                const bool ren = (i & 7) == 7;
                if ((mA16 >> i) & 1u) stepone(evA[i >> 1], i & 1, BA0, BA1, ren);
                if ((mB16 >> i) & 1u) stepone(evB[i >> 1], i & 1, BB0, BB1, ren);
            }
        }
    }

    // ---- two sequential transposes through scratch at +1024 (r8 verbatim) ----
    {
        unsigned* scr = (unsigned*)ebA + 1024;    // 640-dword scratch, stride 20
        unsigned* md  = (unsigned*)ebA;           // M^T A -> [0..511], B -> [512..1023]

        // chunk A
        *(uint2*)&scr[n * 20 + q * 2]            = make_uint2(BA0.u[0], BA0.u[1]);
        *(uint2*)&scr[n * 20 + 8 + q * 2]        = make_uint2(BA0.u[2], BA0.u[3]);
        *(uint2*)&scr[(16 + n) * 20 + q * 2]     = make_uint2(BA1.u[0], BA1.u[1]);
        *(uint2*)&scr[(16 + n) * 20 + 8 + q * 2] = make_uint2(BA1.u[2], BA1.u[3]);
        const unsigned short* NcA = (const unsigned short*)scr;
        unsigned rA[8];
#pragma unroll
        for (int ii = 0; ii < 8; ++ii) {
            const int idx = ii * 64 + lane;
            const int k = idx >> 4, d = idx & 15;
            rA[ii] = (unsigned)NcA[(2 * d) * 40 + k] |
                     ((unsigned)NcA[(2 * d + 1) * 40 + k] << 16);
        }
#pragma unroll
        for (int ii = 0; ii < 8; ++ii) md[ii * 64 + lane] = rA[ii];

        // chunk B (scratch reuse after A's reads complete — program order)
        *(uint2*)&scr[n * 20 + q * 2]            = make_uint2(BB0.u[0], BB0.u[1]);
        *(uint2*)&scr[n * 20 + 8 + q * 2]        = make_uint2(BB0.u[2], BB0.u[3]);
        *(uint2*)&scr[(16 + n) * 20 + q * 2]     = make_uint2(BB1.u[0], BB1.u[1]);
        *(uint2*)&scr[(16 + n) * 20 + 8 + q * 2] = make_uint2(BB1.u[2], BB1.u[3]);
        const unsigned short* NcB = (const unsigned short*)scr;
        unsigned rB[8];
#pragma unroll
        for (int ii = 0; ii < 8; ++ii) {
            const int idx = ii * 64 + lane;
            const int k = idx >> 4, d = idx & 15;
            rB[ii] = (unsigned)NcB[(2 * d) * 40 + k] |
                     ((unsigned)NcB[(2 * d + 1) * 40 + k] << 16);
        }
#pragma unroll
        for (int ii = 0; ii < 8; ++ii) md[512 + ii * 64 + lane] = rB[ii];
    }
    if (lane == 0) {
        sAux[wv]     = (float)eSum * 0.693147180559945f + (float)applied * 3.46573590f;
        sAux[4 + wv] = sc;
    }

    __syncthreads();

    // ---------------- combine (wave 0 only): 8 serial matvecs + logsumexp ----------------
    if (wv == 0) {
        const int h = lane >> 5;
        const int j = lane & 31;

        auto mt = [&](int cc) -> const unsigned* {
            return (const unsigned*)&expAll[cc >> 1][0] + ((cc & 1) << 9);
        };

        // rolling 1-chunk register prefetch of M^T row j halves
        uint4 cA = *(const uint4*)&mt(0)[j * 16 + 8 * h];
        uint4 cB = *(const uint4*)&mt(0)[j * 16 + 8 * h + 4];

        const float a0 = yp[j];                // mirrored in both halves
        const float m0 = __shfl(a0, 0, 64);
        float p = __expf(a0 - m0);             // p[j], mirrored
        float S = m0;

        float scs = 0.0f;
#pragma unroll
        for (int w = 0; w < 4; ++w) { S += sAux[w]; scs += sAux[4 + w]; }

        const int cb = h << 4;                 // column base for this half
#pragma unroll
        for (int cc = 0; cc < NCH; ++cc) {
            uint4 nA = {0, 0, 0, 0}, nB = {0, 0, 0, 0};
            if (cc + 1 < NCH) {
                nA = *(const uint4*)&mt(cc + 1)[j * 16 + 8 * h];
                nB = *(const uint4*)&mt(cc + 1)[j * 16 + 8 * h + 4];
            }
            const float cn = __shfl(p, 0, 64); // old p[0] (deferred renorm)
            const unsigned u0 = cA.x, u1 = cA.y, u2 = cA.z, u3 = cA.w;
            const unsigned u4 = cB.x, u5 = cB.y, u6 = cB.z, u7 = cB.w;
            float acc = 0.0f;
            acc = fmaf(__shfl(p, cb +  0, 64), bf2f_lo(u0), acc);
            acc = fmaf(__shfl(p, cb +  1, 64), bf2f_hi(u0), acc);
            acc = fmaf(__shfl(p, cb +  2, 64), bf2f_lo(u1), acc);
            acc = fmaf(__shfl(p, cb +  3, 64), bf2f_hi(u1), acc);
            acc = fmaf(__shfl(p, cb +  4, 64), bf2f_lo(u2), acc);
            acc = fmaf(__shfl(p, cb +  5, 64), bf2f_hi(u2), acc);
            acc = fmaf(__shfl(p, cb +  6, 64), bf2f_lo(u3), acc);
            acc = fmaf(__shfl(p, cb +  7, 64), bf2f_hi(u3), acc);
            acc = fmaf(__shfl(p, cb +  8, 64), bf2f_lo(u4), acc);
            acc = fmaf(__shfl(p, cb +  9, 64), bf2f_hi(u4), acc);
            acc = fmaf(__shfl(p, cb + 10, 64), bf2f_lo(u5), acc);
            acc = fmaf(__shfl(p, cb + 11, 64), bf2f_hi(u5), acc);
            acc = fmaf(__shfl(p, cb + 12, 64), bf2f_lo(u6), acc);
            acc = fmaf(__shfl(p, cb + 13, 64), bf2f_hi(u6), acc);
            acc = fmaf(__shfl(p, cb + 14, 64), bf2f_lo(u7), acc);
            acc = fmaf(__shfl(p, cb + 15, 64), bf2f_hi(u7), acc);
            acc += __shfl_xor(acc, 32, 64);    // combine halves -> full dot, mirrored
            p = acc * (1.0f / cn);
            S += __logf(cn);
            cA = nA; cB = nB;
        }

        float sp = p;
        sp += __shfl_xor(sp,  1, 64);
        sp += __shfl_xor(sp,  2, 64);
        sp += __shfl_xor(sp,  4, 64);
        sp += __shfl_xor(sp,  8, 64);
        sp += __shfl_xor(sp, 16, 64);

        if (lane == 0) {
            out[seq] = S + __logf(sp) - scs;
        }
    }
}

extern "C" void kernel_launch(void* const* d_in, const int* in_sizes, int n_in,
                              void* d_out, int out_size, void* d_ws, size_t ws_size,
                              hipStream_t stream) {
    const int*   labels = (const int*)  d_in[0];
    const float* y_pred = (const float*)d_in[1];
    const float* trans  = (const float*)d_in[2];
    const float* mask   = (const float*)d_in[3];
    float* out = (float*)d_out;

    crf_fused<<<1024, 256, 0, stream>>>(labels, y_pred, trans, mask, out);
}